// Round 15
// baseline (2035.896 us; speedup 1.0000x reference)
//
#include <hip/hip_runtime.h>
#include <math.h>

typedef unsigned int U32;
typedef unsigned long long U64;

#define NBOX   90000
#define NPIX   10000
#define KDIM   1024
#define CBOT   512
#define PRE_N  6000
#define POST_N 300
#define NWORD  94      // ceil(6000/64)
#define MROWS  6016    // 94*64 rows allocated per column in maskT

// ---------------- workspace layout (byte offsets, all 16B aligned) ----------
#define OFF_H       0ULL          // 10000*512*4   = 20480000
#define OFF_BOXES   20480000ULL   // 90000*4*4     = 1440000
#define OFF_KEYS    21920000ULL   // 90000*4       = 360000
#define OFF_MASKT   22280000ULL   // 94*6016*8     = 4524032 (column-major)
#define OFF_SEL     26804032ULL   // 6000*8        = 48000
#define OFF_SBOX    26852032ULL   // 6000*4*4      = 96000
#define OFF_VALIDW  26948032ULL   // 94*8 -> 768
#define OFF_KEEPW   26948800ULL   // 768
#define OFF_HIST    26949568ULL   // 256*4 -> 1024
#define OFF_CNT     26950592ULL   // 64*4  -> 256
#define OFF_TIE     26950848ULL   // 4096*4 = 16384
#define WS_NEED     26967232ULL

// cnt[] slots: 0=prefix/T  1=target_remaining(->need_ties)  2=c_gt  8=n_gt atomic  9=n_tie atomic

// ============================================================================
// K1: h = relu(feats @ W_b + b_b)  fp32, 128x64 tile, 8x4 acc/thread, BK=16,
// DOUBLE-BUFFERED LDS (one barrier per K-tile; staging store overlaps FMA).
// R14 counters: FETCH fixed at 55MB (XCD remap kept) but dur unchanged ->
// issue/stall-bound: 2 barriers/tile with exposed LDS store was the stall.
// Per-output k-order ascending -> H bitwise identical.
// Also zero-inits hist/cnt/validw (block 0 only).
// ============================================================================
__global__ __launch_bounds__(256, 4) void k_gemm1(
    const float* __restrict__ A, const float* __restrict__ W,
    const float* __restrict__ bias, float* __restrict__ H,
    U32* __restrict__ hist, U32* __restrict__ cnt, U32* __restrict__ validw32)
{
  int t = threadIdx.x;
  if (blockIdx.x == 0) {
    hist[t] = 0;
    if (t < 64)  cnt[t] = (t == 1) ? (U32)PRE_N : 0u;
    if (t < 188) validw32[t] = 0;
  }
  int bid = blockIdx.x;
  int c = bid & 7;                 // XCD under round-robin dispatch
  int s = bid >> 3;                // 0..79
  int x = s / 10;                  // 0..7  column block
  int yy = c * 10 + (s % 10);      // 0..79 row block; XCD-local A slab
  if (yy >= 79) return;            // 8 dead blocks
  __shared__ float As[2][16][132]; // [buf][k][m]
  __shared__ float Bs[2][16][68];  // [buf][k][n]
  int m0 = yy * 128, n0 = x * 64;
  int tm = t >> 4, tn = t & 15;
  int ar = t >> 1, ac = (t & 1) << 3;   // A stage: row ar, cols ac..ac+7
  int bk = t >> 4, bc = (t & 15) << 2;  // B stage: row bk, cols bc..bc+3
  float acc[8][4];
#pragma unroll
  for (int i = 0; i < 8; ++i)
#pragma unroll
    for (int j = 0; j < 4; ++j) acc[i][j] = 0.f;

  // prologue: stage tile 0 into buf 0
  int arow = m0 + ar;
  {
    float4 a0 = make_float4(0.f,0.f,0.f,0.f), a1 = a0;
    if (arow < NPIX) {
      a0 = *(const float4*)&A[(size_t)arow * KDIM + ac];
      a1 = *(const float4*)&A[(size_t)arow * KDIM + ac + 4];
    }
    float4 b0 = *(const float4*)&W[(size_t)bk * CBOT + n0 + bc];
    As[0][ac+0][ar] = a0.x; As[0][ac+1][ar] = a0.y;
    As[0][ac+2][ar] = a0.z; As[0][ac+3][ar] = a0.w;
    As[0][ac+4][ar] = a1.x; As[0][ac+5][ar] = a1.y;
    As[0][ac+6][ar] = a1.z; As[0][ac+7][ar] = a1.w;
    *(float4*)&Bs[0][bk][bc] = b0;
  }
  __syncthreads();

  int cur = 0;
  for (int k0 = 0; k0 < KDIM; k0 += 16) {
    int nxt = cur ^ 1;
    bool more = (k0 + 16) < KDIM;
    float4 na0 = make_float4(0.f,0.f,0.f,0.f), na1 = na0, nb0 = na0;
    if (more) {                      // issue next-tile loads (hide under FMA)
      int kn = k0 + 16;
      if (arow < NPIX) {
        na0 = *(const float4*)&A[(size_t)arow * KDIM + kn + ac];
        na1 = *(const float4*)&A[(size_t)arow * KDIM + kn + ac + 4];
      }
      nb0 = *(const float4*)&W[(size_t)(kn + bk) * CBOT + n0 + bc];
    }
#pragma unroll
    for (int kk = 0; kk < 16; ++kk) {
      float4 av0 = *(float4*)&As[cur][kk][tm*8];   // 16-lane broadcast
      float4 av1 = *(float4*)&As[cur][kk][tm*8+4];
      float4 bv0 = *(float4*)&Bs[cur][kk][tn*4];   // 2-way aliasing: free
      float am[8] = {av0.x,av0.y,av0.z,av0.w,av1.x,av1.y,av1.z,av1.w};
      float bm[4] = {bv0.x,bv0.y,bv0.z,bv0.w};
#pragma unroll
      for (int i = 0; i < 8; ++i)
#pragma unroll
        for (int j = 0; j < 4; ++j)
          acc[i][j] = fmaf(am[i], bm[j], acc[i][j]);
    }
    if (more) {                      // store into the OTHER buffer: no race
      As[nxt][ac+0][ar] = na0.x; As[nxt][ac+1][ar] = na0.y;
      As[nxt][ac+2][ar] = na0.z; As[nxt][ac+3][ar] = na0.w;
      As[nxt][ac+4][ar] = na1.x; As[nxt][ac+5][ar] = na1.y;
      As[nxt][ac+6][ar] = na1.z; As[nxt][ac+7][ar] = na1.w;
      *(float4*)&Bs[nxt][bk][bc] = nb0;
    }
    __syncthreads();                 // ONE barrier per tile
    cur = nxt;
  }
  float4 bb = *(const float4*)&bias[n0 + tn*4];
  float bm[4] = {bb.x, bb.y, bb.z, bb.w};
#pragma unroll
  for (int i = 0; i < 8; ++i) {
    int r = m0 + tm*8 + i;
    if (r < NPIX) {
      float4 o;
      o.x = fmaxf(acc[i][0] + bm[0], 0.f);
      o.y = fmaxf(acc[i][1] + bm[1], 0.f);
      o.z = fmaxf(acc[i][2] + bm[2], 0.f);
      o.w = fmaxf(acc[i][3] + bm[3], 0.f);
      *(float4*)&H[(size_t)r * CBOT + n0 + tn*4] = o;
    }
  }
}

// ============================================================================
// K2: cls = sigmoid(h@W_cls+b_cls), reg = h@W_reg+b_reg  (4 pixels / block)
// ============================================================================
__global__ __launch_bounds__(256) void k_heads(
    const float* __restrict__ H, const float* __restrict__ Wc,
    const float* __restrict__ bc, const float* __restrict__ Wr,
    const float* __restrict__ br, float* __restrict__ outCls,
    float* __restrict__ outReg)
{
  __shared__ float hs[4][516];
  int t = threadIdx.x;
  int p0 = blockIdx.x * 4;
  for (int q = t; q < 512; q += 256) {
    int row = q >> 7, off = (q & 127) << 2;
    *(float4*)&hs[row][off] = *(const float4*)&H[(size_t)(p0 + row) * CBOT + off];
  }
  __syncthreads();
  if (t < 180) {
    int pl = t / 45, c = t % 45;
    const float* wp; int stride; float bval;
    if (c < 9) { wp = Wc + c;       stride = 9;  bval = bc[c]; }
    else       { wp = Wr + (c - 9); stride = 36; bval = br[c - 9]; }
    float s = 0.f;
    const float* hrow = hs[pl];
    for (int k = 0; k < CBOT; k += 4) {
      float4 hv = *(const float4*)&hrow[k];
      s = fmaf(hv.x, wp[(size_t)(k+0)*stride], s);
      s = fmaf(hv.y, wp[(size_t)(k+1)*stride], s);
      s = fmaf(hv.z, wp[(size_t)(k+2)*stride], s);
      s = fmaf(hv.w, wp[(size_t)(k+3)*stride], s);
    }
    s += bval;
    int p = p0 + pl;
    if (c < 9) outCls[(size_t)p*9 + c] = 1.f / (1.f + expf(-s));
    else       outReg[(size_t)p*36 + (c - 9)] = s;
  }
}

// ============================================================================
// K3: decode boxes, size filter, sortable keys, level-0 histogram
// ============================================================================
__global__ __launch_bounds__(256) void k_decode(
    const float* __restrict__ outCls, const float* __restrict__ outReg,
    const float* __restrict__ ancs, float* __restrict__ boxes,
    U32* __restrict__ keys, U32* __restrict__ hist)
{
  __shared__ U32 lh[256];
  int t = threadIdx.x;
  int tid = blockIdx.x * 256 + t;
  lh[t] = 0;
  __syncthreads();
  if (tid < NBOX) {
    float sc = outCls[tid];
    float4 of = *(const float4*)&outReg[(size_t)tid*4];
    float4 an = *(const float4*)&ancs[(size_t)tid*4];
    float cx = an.x + of.x * an.z;
    float cy = an.y + of.y * an.w;
    float ww = an.z * expf(of.z);
    float hh = an.w * expf(of.w);
    float x1 = fminf(fmaxf(cx - ww * 0.5f, 0.f), 1.f);
    float y1 = fminf(fmaxf(cy - hh * 0.5f, 0.f), 1.f);
    float x2 = fminf(fmaxf(cx + ww * 0.5f, 0.f), 1.f);
    float y2 = fminf(fmaxf(cy + hh * 0.5f, 0.f), 1.f);
    bool ok = ((x2 - x1) * 100.f >= 1.f) && ((y2 - y1) * 100.f >= 1.f);
    float msc = ok ? sc : -1.f;
    U32 u = __float_as_uint(msc);
    U32 key = (u & 0x80000000u) ? ~u : (u | 0x80000000u);
    keys[tid] = key;
    *(float4*)&boxes[(size_t)tid*4] = make_float4(x1, y1, x2, y2);
    atomicAdd(&lh[key >> 24], 1u);
  }
  __syncthreads();
  if (lh[t]) atomicAdd(&hist[t], lh[t]);
}

// ============================================================================
// K4: radix-select scan step (one per level). Picks digit, updates prefix /
// remaining target / count-above, zeroes hist for next level.
// ============================================================================
__global__ __launch_bounds__(256) void k_scan(
    U32* __restrict__ hist, U32* __restrict__ cnt, int level)
{
  __shared__ U32 lh[256];
  int t = threadIdx.x;
  lh[t] = hist[t];
  __syncthreads();
  if (t == 0) {
    U32 target = cnt[1];
    U32 cum = 0;
    int d = 255;
    while (d > 0) {
      U32 hh = lh[d];
      if (cum + hh >= target) break;
      cum += hh; --d;
    }
    cnt[0] |= ((U32)d) << (24 - 8*level);
    cnt[1] = target - cum;
    cnt[2] += cum;
  }
  __syncthreads();
  hist[t] = 0;
}

// ============================================================================
// K5: filtered histogram for levels 1..3
// ============================================================================
__global__ __launch_bounds__(256) void k_hist(
    const U32* __restrict__ keys, U32* __restrict__ hist,
    const U32* __restrict__ cnt, int level)
{
  __shared__ U32 lh[256];
  int t = threadIdx.x;
  int tid = blockIdx.x * 256 + t;
  lh[t] = 0;
  __syncthreads();
  if (tid < NBOX) {
    U32 k = keys[tid];
    U32 prefix = cnt[0];
    int shift = 32 - 8*level;
    if ((k >> shift) == (prefix >> shift)) {
      U32 bin = (k >> (24 - 8*level)) & 0xFFu;
      atomicAdd(&lh[bin], 1u);
    }
  }
  __syncthreads();
  if (lh[t]) atomicAdd(&hist[t], lh[t]);
}

// ============================================================================
// K6: compact: keys > T -> sel (unordered; rank pass sorts later);
//     keys == T -> tie buffer.
// ============================================================================
__global__ __launch_bounds__(256) void k_compact(
    const U32* __restrict__ keys, U32* __restrict__ cnt,
    U64* __restrict__ sel, U32* __restrict__ tiebuf)
{
  int tid = blockIdx.x * 256 + threadIdx.x;
  if (tid >= NBOX) return;
  U32 k = keys[tid];
  U32 T = cnt[0];
  if (k > T) {
    U32 p = atomicAdd(&cnt[8], 1u);
    sel[p] = ((U64)k << 32) | (U64)(0xFFFFFFFFu - (U32)tid);
  } else if (k == T) {
    U32 p = atomicAdd(&cnt[9], 1u);
    if (p < 4096) tiebuf[p] = (U32)tid;
  }
}

// ============================================================================
// K7: resolve ==T ties by smallest index (stable top_k semantics)
// ============================================================================
__global__ __launch_bounds__(256) void k_ties(
    U32* __restrict__ cnt, const U32* __restrict__ tiebuf, U64* __restrict__ sel)
{
  __shared__ U32 tb[4096];
  int t = threadIdx.x;
  U32 m = cnt[9]; if (m > 4096u) m = 4096u;
  U32 need = cnt[1];
  U32 cgt  = cnt[2];
  U32 T    = cnt[0];
  for (U32 j = t; j < m; j += 256) tb[j] = tiebuf[j];
  __syncthreads();
  for (U32 x = t; x < m; x += 256) {
    U32 my = tb[x];
    U32 r = 0;
    for (U32 j = 0; j < m; ++j) r += (tb[j] < my) ? 1u : 0u;
    if (r < need) sel[cgt + r] = ((U64)T << 32) | (U64)(0xFFFFFFFFu - my);
  }
}

// ============================================================================
// K8: exact rank of each selected element (score desc, idx asc) -> sorted
// boxes + packed valid bits. 36M u64 compares, LDS-staged. Order-invariant
// wrt sel's (atomic-nondeterministic) storage order.
// ============================================================================
__global__ __launch_bounds__(256) void k_rank(
    const U64* __restrict__ sel, const float* __restrict__ boxes,
    float* __restrict__ sboxes, U64* __restrict__ validw)
{
  __shared__ U64 ss[PRE_N];
  int t = threadIdx.x;
  for (int j = t; j < PRE_N; j += 256) ss[j] = sel[j];
  __syncthreads();
  int i = blockIdx.x * 256 + t;
  if (i >= PRE_N) return;
  U64 C = ss[i];
  int r = 0;
  for (int j = 0; j < PRE_N; ++j) r += (ss[j] > C) ? 1 : 0;
  U32 key = (U32)(C >> 32);
  U32 idx = 0xFFFFFFFFu - (U32)(C & 0xFFFFFFFFull);
  *(float4*)&sboxes[(size_t)r*4] = *(const float4*)&boxes[(size_t)idx*4];
  if (key & 0x80000000u)
    atomicOr(&validw[r >> 6], 1ull << (r & 63));
}

// ============================================================================
// K9: IoU > 0.7 bitmask, COLUMN-word-major: maskT[cw*MROWS + i] bit x =
//     iou(row i, box cw*64+x) > thr. Upper triangle + diagonal only (NMS
//     reads only i >= cw*64). Rows 6000..6015 in touched blocks written as 0.
// ============================================================================
__global__ __launch_bounds__(256) void k_mask(
    const float* __restrict__ sboxes, U64* __restrict__ maskT)
{
  int cw = blockIdx.x, rg = blockIdx.y;
  if (rg < cw) return;                       // lower triangle unused by NMS
  int t = threadIdx.x;
  int lane = t & 63, wv = t >> 6;
  int col = cw * 64 + lane;
  int cc = (col < PRE_N) ? col : (PRE_N - 1);
  float4 cb = *(const float4*)&sboxes[(size_t)cc*4];
  float areaC = (cb.z - cb.x) * (cb.w - cb.y);
  bool colok = (col < PRE_N);
  for (int rr = wv; rr < 64; rr += 4) {
    int row = rg * 64 + rr;
    U64 word = 0;
    if (row < PRE_N) {
      float4 rb = *(const float4*)&sboxes[(size_t)row*4];
      float areaR = (rb.z - rb.x) * (rb.w - rb.y);
      float ix1 = fmaxf(rb.x, cb.x), iy1 = fmaxf(rb.y, cb.y);
      float ix2 = fminf(rb.z, cb.z), iy2 = fminf(rb.w, cb.w);
      float inter = fmaxf(ix2 - ix1, 0.f) * fmaxf(iy2 - iy1, 0.f);
      float uni = areaR + areaC - inter;
      float iou = inter / fmaxf(uni, 1e-9f);
      word = __ballot(colok && (iou > 0.7f));
    }
    if (lane == 0) maskT[(size_t)cw * MROWS + row] = word;
  }
}

// ============================================================================
// K10: sequential-equivalent NMS — 8 WAVES, barrier phases. R15 change: the
// apply-phase mask loads are HOISTED above the decide (they don't depend on
// keep) so the ~600cy L2 round-trip overlaps decide+barrier; consume is
// unconditional (m & keep self-gates, and avoids the compiler sinking the
// loads into a guarded block). Bitwise-deterministic, reference scan order.
// ============================================================================
__global__ __launch_bounds__(512, 1) void k_nms(
    const U64* __restrict__ maskT, const U64* __restrict__ validw,
    U64* __restrict__ keepw)
{
  __shared__ U32 sup[MROWS];
  __shared__ U64 vws[NWORD];
  __shared__ U64 kwsh;
  int t = threadIdx.x;                       // 0..511
  int wave = t >> 6, lane = t & 63;
  for (int i = t; i < MROWS; i += 512) sup[i] = 0;
  if (t < NWORD) vws[t] = validw[t];
  U64 low = (lane == 0) ? 0ull : (~0ull >> (64 - lane));
  U64 intra = (wave == 0) ? maskT[lane] : 0ull;   // chunk 0 diagonal word
  __syncthreads();
  for (int c = 0; c < NWORD; ++c) {
    const U64* colp = maskT + (size_t)c * MROWS;
    int base = (c + 1) * 64;
    // ---- hoisted apply loads (independent of decide) ----
    U64 m[12];                               // 12*512 = 6144 >= max rows
#pragma unroll
    for (int q = 0; q < 12; ++q) {
      int i = base + q * 512 + t;
      int ic = (i > MROWS - 1) ? (MROWS - 1) : i;
      m[q] = colp[ic];
    }
    if (wave == 0) {
      // ---- decide (wave-0 local; ballots are per-wave) ----
      U64 vw = vws[c];
      bool alive = (((vw >> lane) & 1ull) != 0ull) && (sup[c * 64 + lane] == 0u);
      U64 aliveW = __ballot(alive);
      bool myconf = alive && ((intra & aliveW & low) != 0ull);
      U64 confW = __ballot(myconf);
      U64 keep = aliveW & ~confW;            // non-conflicted alive are kept
      U64 rem = confW;                       // resolve conflicted ascending
      while (rem) {
        int b = __ffsll((unsigned long long)rem) - 1;
        rem &= rem - 1;
        U64 Z = __ballot((intra & keep & low) == 0ull);
        if ((Z >> b) & 1ull) keep |= (1ull << b);
      }
      if (lane == 0) { keepw[c] = keep; kwsh = keep; }
      if (c + 1 < NWORD)                     // prefetch next diagonal word
        intra = maskT[(size_t)(c + 1) * MROWS + (c + 1) * 64 + lane];
    }
    __syncthreads();                         // kwsh + sup reads ordered
    U64 keep = kwsh;                         // 0 -> stores self-disable
#pragma unroll
    for (int q = 0; q < 12; ++q) {
      int i = base + q * 512 + t;
      if (i < PRE_N && (m[q] & keep)) sup[i] = 1u;
    }
    __syncthreads();                         // sup[] complete before decide c+1
  }
}

// ============================================================================
// K11: proposals: prefix-popcount ranks, first 300 kept boxes, zeros elsewhere
// ============================================================================
__global__ __launch_bounds__(256) void k_out(
    const U64* __restrict__ keepw, const float* __restrict__ sboxes,
    float* __restrict__ prop)
{
  __shared__ U64 kw[NWORD];
  __shared__ U32 pre[NWORD + 1];
  int t = threadIdx.x;
  if (t < NWORD) kw[t] = keepw[t];
  __syncthreads();
  if (t == 0) {
    U32 s = 0;
    for (int w = 0; w < NWORD; ++w) { pre[w] = s; s += (U32)__popcll(kw[w]); }
    pre[NWORD] = s;
  }
  for (int x = t; x < POST_N * 4; x += 256) prop[x] = 0.f;
  __syncthreads();
  for (int i = t; i < PRE_N; i += 256) {
    int w = i >> 6, b = i & 63;
    if ((kw[w] >> b) & 1ull) {
      U64 lowb = (b == 0) ? 0ull : (~0ull >> (64 - b));
      U32 r = pre[w] + (U32)__popcll(kw[w] & lowb);
      if (r < POST_N)
        *(float4*)&prop[(size_t)r*4] = *(const float4*)&sboxes[(size_t)i*4];
    }
  }
}

// ============================================================================
extern "C" void kernel_launch(void* const* d_in, const int* in_sizes, int n_in,
                              void* d_out, int out_size, void* d_ws, size_t ws_size,
                              hipStream_t stream)
{
  (void)in_sizes; (void)n_in; (void)out_size;
  if (ws_size < WS_NEED) return;   // scratch too small; bail safely

  const float* feats = (const float*)d_in[0];
  const float* ancs  = (const float*)d_in[1];
  const float* W_b   = (const float*)d_in[3];
  const float* b_b   = (const float*)d_in[4];
  const float* W_cls = (const float*)d_in[5];
  const float* b_cls = (const float*)d_in[6];
  const float* W_reg = (const float*)d_in[7];
  const float* b_reg = (const float*)d_in[8];

  float* out    = (float*)d_out;
  float* outCls = out;                 // 90000
  float* outReg = out + 90000;         // 360000
  float* prop   = out + 450000;        // 1200

  char* ws = (char*)d_ws;
  float* H      = (float*)(ws + OFF_H);
  float* boxes  = (float*)(ws + OFF_BOXES);
  U32*   keys   = (U32*)  (ws + OFF_KEYS);
  U64*   maskT  = (U64*)  (ws + OFF_MASKT);
  U64*   sel    = (U64*)  (ws + OFF_SEL);
  float* sboxes = (float*)(ws + OFF_SBOX);
  U64*   validw = (U64*)  (ws + OFF_VALIDW);
  U64*   keepw  = (U64*)  (ws + OFF_KEEPW);
  U32*   hist   = (U32*)  (ws + OFF_HIST);
  U32*   cnt    = (U32*)  (ws + OFF_CNT);
  U32*   tiebuf = (U32*)  (ws + OFF_TIE);

  k_gemm1<<<dim3(640), dim3(256), 0, stream>>>(feats, W_b, b_b, H,
                                               hist, cnt, (U32*)validw);
  k_heads<<<dim3(2500), dim3(256), 0, stream>>>(H, W_cls, b_cls, W_reg, b_reg,
                                                outCls, outReg);
  k_decode<<<dim3(352), dim3(256), 0, stream>>>(outCls, outReg, ancs,
                                                boxes, keys, hist);
  k_scan<<<dim3(1), dim3(256), 0, stream>>>(hist, cnt, 0);
  for (int lv = 1; lv <= 3; ++lv) {
    k_hist<<<dim3(352), dim3(256), 0, stream>>>(keys, hist, cnt, lv);
    k_scan<<<dim3(1), dim3(256), 0, stream>>>(hist, cnt, lv);
  }
  k_compact<<<dim3(352), dim3(256), 0, stream>>>(keys, cnt, sel, tiebuf);
  k_ties<<<dim3(1), dim3(256), 0, stream>>>(cnt, tiebuf, sel);
  k_rank<<<dim3(24), dim3(256), 0, stream>>>(sel, boxes, sboxes, validw);
  k_mask<<<dim3(94, 94), dim3(256), 0, stream>>>(sboxes, maskT);
  k_nms<<<dim3(1), dim3(512), 0, stream>>>(maskT, validw, keepw);
  k_out<<<dim3(1), dim3(256), 0, stream>>>(keepw, sboxes, prop);
}

// Round 16
// 530.287 us; speedup vs baseline: 3.8392x; 3.8392x over previous
//
#include <hip/hip_runtime.h>
#include <math.h>

typedef unsigned int U32;
typedef unsigned long long U64;

#define NBOX   90000
#define NPIX   10000
#define KDIM   1024
#define CBOT   512
#define PRE_N  6000
#define POST_N 300
#define NWORD  94      // ceil(6000/64)
#define MROWS  6016    // 94*64 rows allocated per column in maskT

// ---------------- workspace layout (byte offsets, all 16B aligned) ----------
#define OFF_H       0ULL          // 10000*512*4   = 20480000
#define OFF_BOXES   20480000ULL   // 90000*4*4     = 1440000
#define OFF_KEYS    21920000ULL   // 90000*4       = 360000
#define OFF_MASKT   22280000ULL   // 94*6016*8     = 4524032 (column-major)
#define OFF_SEL     26804032ULL   // 6000*8        = 48000
#define OFF_SBOX    26852032ULL   // 6000*4*4      = 96000
#define OFF_VALIDW  26948032ULL   // 94*8 -> 768
#define OFF_KEEPW   26948800ULL   // 768
#define OFF_HIST    26949568ULL   // 256*4 -> 1024
#define OFF_CNT     26950592ULL   // 64*4  -> 256
#define OFF_TIE     26950848ULL   // 4096*4 = 16384
#define WS_NEED     26967232ULL

// cnt[] slots: 0=prefix/T  1=target_remaining(->need_ties)  2=c_gt  8=n_gt atomic  9=n_tie atomic

// ============================================================================
// K1: h = relu(feats @ W_b + b_b)  fp32, 128x64 tile, 8x4 acc/thread, BK=16.
// EXACT R14 version (measured 178us, VGPR=48, acc in AGPRs, zero spill).
// R15 lesson: double-buffered LDS (runtime cur idx + loads live across the
// 512-FMA window) made the allocator spill acc to scratch -> 4.7GB writes,
// 1780us. DO NOT add live state across the FMA loop on this toolchain.
// XCD remap (T1) keeps A slab L2-resident: FETCH 55MB (~ideal).
// Also zero-inits hist/cnt/validw (block 0 only).
// ============================================================================
__global__ __launch_bounds__(256, 4) void k_gemm1(
    const float* __restrict__ A, const float* __restrict__ W,
    const float* __restrict__ bias, float* __restrict__ H,
    U32* __restrict__ hist, U32* __restrict__ cnt, U32* __restrict__ validw32)
{
  int t = threadIdx.x;
  if (blockIdx.x == 0) {
    hist[t] = 0;
    if (t < 64)  cnt[t] = (t == 1) ? (U32)PRE_N : 0u;
    if (t < 188) validw32[t] = 0;
  }
  int bid = blockIdx.x;
  int c = bid & 7;                 // XCD under round-robin dispatch
  int s = bid >> 3;                // 0..79
  int x = s / 10;                  // 0..7  column block
  int yy = c * 10 + (s % 10);      // 0..79 row block; XCD-local A slab
  if (yy >= 79) return;            // 8 dead blocks
  __shared__ float As[16][132];   // [k][m], pad: bank stride 4 per k-row
  __shared__ float Bs[16][68];    // [k][n], 64 cols + pad
  int m0 = yy * 128, n0 = x * 64;
  int tm = t >> 4, tn = t & 15;
  int ar = t >> 1, ac = (t & 1) << 3;   // A stage: row ar, cols ac..ac+7
  int bk = t >> 4, bc = (t & 15) << 2;  // B stage: row bk, cols bc..bc+3
  float acc[8][4];
#pragma unroll
  for (int i = 0; i < 8; ++i)
#pragma unroll
    for (int j = 0; j < 4; ++j) acc[i][j] = 0.f;

  // prologue: first tile's loads
  int arow = m0 + ar;
  float4 a0 = make_float4(0.f,0.f,0.f,0.f), a1 = a0;
  if (arow < NPIX) {
    a0 = *(const float4*)&A[(size_t)arow * KDIM + ac];
    a1 = *(const float4*)&A[(size_t)arow * KDIM + ac + 4];
  }
  float4 b0 = *(const float4*)&W[(size_t)bk * CBOT + n0 + bc];

  for (int k0 = 0; k0 < KDIM; k0 += 16) {
    __syncthreads();                 // prior FMA readers done
    As[ac+0][ar] = a0.x; As[ac+1][ar] = a0.y; As[ac+2][ar] = a0.z; As[ac+3][ar] = a0.w;
    As[ac+4][ar] = a1.x; As[ac+5][ar] = a1.y; As[ac+6][ar] = a1.z; As[ac+7][ar] = a1.w;
    *(float4*)&Bs[bk][bc] = b0;
    __syncthreads();
    if (k0 + 16 < KDIM) {            // issue next-tile loads BEFORE FMA loop
      int kn = k0 + 16;
      if (arow < NPIX) {
        a0 = *(const float4*)&A[(size_t)arow * KDIM + kn + ac];
        a1 = *(const float4*)&A[(size_t)arow * KDIM + kn + ac + 4];
      }
      b0 = *(const float4*)&W[(size_t)(kn + bk) * CBOT + n0 + bc];
    }
#pragma unroll
    for (int kk = 0; kk < 16; ++kk) {
      float4 av0 = *(float4*)&As[kk][tm*8];      // 16-lane broadcast, no conflict
      float4 av1 = *(float4*)&As[kk][tm*8+4];
      float4 bv0 = *(float4*)&Bs[kk][tn*4];      // 2-way aliasing: free
      float am[8] = {av0.x,av0.y,av0.z,av0.w,av1.x,av1.y,av1.z,av1.w};
      float bm[4] = {bv0.x,bv0.y,bv0.z,bv0.w};
#pragma unroll
      for (int i = 0; i < 8; ++i)
#pragma unroll
        for (int j = 0; j < 4; ++j)
          acc[i][j] = fmaf(am[i], bm[j], acc[i][j]);
    }
  }
  float4 bb = *(const float4*)&bias[n0 + tn*4];
  float bm[4] = {bb.x, bb.y, bb.z, bb.w};
#pragma unroll
  for (int i = 0; i < 8; ++i) {
    int r = m0 + tm*8 + i;
    if (r < NPIX) {
      float4 o;
      o.x = fmaxf(acc[i][0] + bm[0], 0.f);
      o.y = fmaxf(acc[i][1] + bm[1], 0.f);
      o.z = fmaxf(acc[i][2] + bm[2], 0.f);
      o.w = fmaxf(acc[i][3] + bm[3], 0.f);
      *(float4*)&H[(size_t)r * CBOT + n0 + tn*4] = o;
    }
  }
}

// ============================================================================
// K2: cls = sigmoid(h@W_cls+b_cls), reg = h@W_reg+b_reg  (4 pixels / block)
// ============================================================================
__global__ __launch_bounds__(256) void k_heads(
    const float* __restrict__ H, const float* __restrict__ Wc,
    const float* __restrict__ bc, const float* __restrict__ Wr,
    const float* __restrict__ br, float* __restrict__ outCls,
    float* __restrict__ outReg)
{
  __shared__ float hs[4][516];
  int t = threadIdx.x;
  int p0 = blockIdx.x * 4;
  for (int q = t; q < 512; q += 256) {
    int row = q >> 7, off = (q & 127) << 2;
    *(float4*)&hs[row][off] = *(const float4*)&H[(size_t)(p0 + row) * CBOT + off];
  }
  __syncthreads();
  if (t < 180) {
    int pl = t / 45, c = t % 45;
    const float* wp; int stride; float bval;
    if (c < 9) { wp = Wc + c;       stride = 9;  bval = bc[c]; }
    else       { wp = Wr + (c - 9); stride = 36; bval = br[c - 9]; }
    float s = 0.f;
    const float* hrow = hs[pl];
    for (int k = 0; k < CBOT; k += 4) {
      float4 hv = *(const float4*)&hrow[k];
      s = fmaf(hv.x, wp[(size_t)(k+0)*stride], s);
      s = fmaf(hv.y, wp[(size_t)(k+1)*stride], s);
      s = fmaf(hv.z, wp[(size_t)(k+2)*stride], s);
      s = fmaf(hv.w, wp[(size_t)(k+3)*stride], s);
    }
    s += bval;
    int p = p0 + pl;
    if (c < 9) outCls[(size_t)p*9 + c] = 1.f / (1.f + expf(-s));
    else       outReg[(size_t)p*36 + (c - 9)] = s;
  }
}

// ============================================================================
// K3: decode boxes, size filter, sortable keys, level-0 histogram
// ============================================================================
__global__ __launch_bounds__(256) void k_decode(
    const float* __restrict__ outCls, const float* __restrict__ outReg,
    const float* __restrict__ ancs, float* __restrict__ boxes,
    U32* __restrict__ keys, U32* __restrict__ hist)
{
  __shared__ U32 lh[256];
  int t = threadIdx.x;
  int tid = blockIdx.x * 256 + t;
  lh[t] = 0;
  __syncthreads();
  if (tid < NBOX) {
    float sc = outCls[tid];
    float4 of = *(const float4*)&outReg[(size_t)tid*4];
    float4 an = *(const float4*)&ancs[(size_t)tid*4];
    float cx = an.x + of.x * an.z;
    float cy = an.y + of.y * an.w;
    float ww = an.z * expf(of.z);
    float hh = an.w * expf(of.w);
    float x1 = fminf(fmaxf(cx - ww * 0.5f, 0.f), 1.f);
    float y1 = fminf(fmaxf(cy - hh * 0.5f, 0.f), 1.f);
    float x2 = fminf(fmaxf(cx + ww * 0.5f, 0.f), 1.f);
    float y2 = fminf(fmaxf(cy + hh * 0.5f, 0.f), 1.f);
    bool ok = ((x2 - x1) * 100.f >= 1.f) && ((y2 - y1) * 100.f >= 1.f);
    float msc = ok ? sc : -1.f;
    U32 u = __float_as_uint(msc);
    U32 key = (u & 0x80000000u) ? ~u : (u | 0x80000000u);
    keys[tid] = key;
    *(float4*)&boxes[(size_t)tid*4] = make_float4(x1, y1, x2, y2);
    atomicAdd(&lh[key >> 24], 1u);
  }
  __syncthreads();
  if (lh[t]) atomicAdd(&hist[t], lh[t]);
}

// ============================================================================
// K4: radix-select scan step (one per level). Picks digit, updates prefix /
// remaining target / count-above, zeroes hist for next level.
// ============================================================================
__global__ __launch_bounds__(256) void k_scan(
    U32* __restrict__ hist, U32* __restrict__ cnt, int level)
{
  __shared__ U32 lh[256];
  int t = threadIdx.x;
  lh[t] = hist[t];
  __syncthreads();
  if (t == 0) {
    U32 target = cnt[1];
    U32 cum = 0;
    int d = 255;
    while (d > 0) {
      U32 hh = lh[d];
      if (cum + hh >= target) break;
      cum += hh; --d;
    }
    cnt[0] |= ((U32)d) << (24 - 8*level);
    cnt[1] = target - cum;
    cnt[2] += cum;
  }
  __syncthreads();
  hist[t] = 0;
}

// ============================================================================
// K5: filtered histogram for levels 1..3
// ============================================================================
__global__ __launch_bounds__(256) void k_hist(
    const U32* __restrict__ keys, U32* __restrict__ hist,
    const U32* __restrict__ cnt, int level)
{
  __shared__ U32 lh[256];
  int t = threadIdx.x;
  int tid = blockIdx.x * 256 + t;
  lh[t] = 0;
  __syncthreads();
  if (tid < NBOX) {
    U32 k = keys[tid];
    U32 prefix = cnt[0];
    int shift = 32 - 8*level;
    if ((k >> shift) == (prefix >> shift)) {
      U32 bin = (k >> (24 - 8*level)) & 0xFFu;
      atomicAdd(&lh[bin], 1u);
    }
  }
  __syncthreads();
  if (lh[t]) atomicAdd(&hist[t], lh[t]);
}

// ============================================================================
// K6: compact: keys > T -> sel (unordered; rank pass sorts later);
//     keys == T -> tie buffer.
// ============================================================================
__global__ __launch_bounds__(256) void k_compact(
    const U32* __restrict__ keys, U32* __restrict__ cnt,
    U64* __restrict__ sel, U32* __restrict__ tiebuf)
{
  int tid = blockIdx.x * 256 + threadIdx.x;
  if (tid >= NBOX) return;
  U32 k = keys[tid];
  U32 T = cnt[0];
  if (k > T) {
    U32 p = atomicAdd(&cnt[8], 1u);
    sel[p] = ((U64)k << 32) | (U64)(0xFFFFFFFFu - (U32)tid);
  } else if (k == T) {
    U32 p = atomicAdd(&cnt[9], 1u);
    if (p < 4096) tiebuf[p] = (U32)tid;
  }
}

// ============================================================================
// K7: resolve ==T ties by smallest index (stable top_k semantics)
// ============================================================================
__global__ __launch_bounds__(256) void k_ties(
    U32* __restrict__ cnt, const U32* __restrict__ tiebuf, U64* __restrict__ sel)
{
  __shared__ U32 tb[4096];
  int t = threadIdx.x;
  U32 m = cnt[9]; if (m > 4096u) m = 4096u;
  U32 need = cnt[1];
  U32 cgt  = cnt[2];
  U32 T    = cnt[0];
  for (U32 j = t; j < m; j += 256) tb[j] = tiebuf[j];
  __syncthreads();
  for (U32 x = t; x < m; x += 256) {
    U32 my = tb[x];
    U32 r = 0;
    for (U32 j = 0; j < m; ++j) r += (tb[j] < my) ? 1u : 0u;
    if (r < need) sel[cgt + r] = ((U64)T << 32) | (U64)(0xFFFFFFFFu - my);
  }
}

// ============================================================================
// K8: exact rank of each selected element (score desc, idx asc) -> sorted
// boxes + packed valid bits. 36M u64 compares, LDS-staged. Order-invariant
// wrt sel's (atomic-nondeterministic) storage order.
// ============================================================================
__global__ __launch_bounds__(256) void k_rank(
    const U64* __restrict__ sel, const float* __restrict__ boxes,
    float* __restrict__ sboxes, U64* __restrict__ validw)
{
  __shared__ U64 ss[PRE_N];
  int t = threadIdx.x;
  for (int j = t; j < PRE_N; j += 256) ss[j] = sel[j];
  __syncthreads();
  int i = blockIdx.x * 256 + t;
  if (i >= PRE_N) return;
  U64 C = ss[i];
  int r = 0;
  for (int j = 0; j < PRE_N; ++j) r += (ss[j] > C) ? 1 : 0;
  U32 key = (U32)(C >> 32);
  U32 idx = 0xFFFFFFFFu - (U32)(C & 0xFFFFFFFFull);
  *(float4*)&sboxes[(size_t)r*4] = *(const float4*)&boxes[(size_t)idx*4];
  if (key & 0x80000000u)
    atomicOr(&validw[r >> 6], 1ull << (r & 63));
}

// ============================================================================
// K9: IoU > 0.7 bitmask, COLUMN-word-major: maskT[cw*MROWS + i] bit x =
//     iou(row i, box cw*64+x) > thr. Upper triangle + diagonal only (NMS
//     reads only i >= cw*64). Rows 6000..6015 in touched blocks written as 0.
// ============================================================================
__global__ __launch_bounds__(256) void k_mask(
    const float* __restrict__ sboxes, U64* __restrict__ maskT)
{
  int cw = blockIdx.x, rg = blockIdx.y;
  if (rg < cw) return;                       // lower triangle unused by NMS
  int t = threadIdx.x;
  int lane = t & 63, wv = t >> 6;
  int col = cw * 64 + lane;
  int cc = (col < PRE_N) ? col : (PRE_N - 1);
  float4 cb = *(const float4*)&sboxes[(size_t)cc*4];
  float areaC = (cb.z - cb.x) * (cb.w - cb.y);
  bool colok = (col < PRE_N);
  for (int rr = wv; rr < 64; rr += 4) {
    int row = rg * 64 + rr;
    U64 word = 0;
    if (row < PRE_N) {
      float4 rb = *(const float4*)&sboxes[(size_t)row*4];
      float areaR = (rb.z - rb.x) * (rb.w - rb.y);
      float ix1 = fmaxf(rb.x, cb.x), iy1 = fmaxf(rb.y, cb.y);
      float ix2 = fminf(rb.z, cb.z), iy2 = fminf(rb.w, cb.w);
      float inter = fmaxf(ix2 - ix1, 0.f) * fmaxf(iy2 - iy1, 0.f);
      float uni = areaR + areaC - inter;
      float iou = inter / fmaxf(uni, 1e-9f);
      word = __ballot(colok && (iou > 0.7f));
    }
    if (lane == 0) maskT[(size_t)cw * MROWS + row] = word;
  }
}

// ============================================================================
// K10: sequential-equivalent NMS — 8 WAVES, barrier phases, apply-phase mask
// loads hoisted above decide (overlap L2 latency with decide+barrier).
// Bitwise-deterministic, reference scan order.
// ============================================================================
__global__ __launch_bounds__(512, 1) void k_nms(
    const U64* __restrict__ maskT, const U64* __restrict__ validw,
    U64* __restrict__ keepw)
{
  __shared__ U32 sup[MROWS];
  __shared__ U64 vws[NWORD];
  __shared__ U64 kwsh;
  int t = threadIdx.x;                       // 0..511
  int wave = t >> 6, lane = t & 63;
  for (int i = t; i < MROWS; i += 512) sup[i] = 0;
  if (t < NWORD) vws[t] = validw[t];
  U64 low = (lane == 0) ? 0ull : (~0ull >> (64 - lane));
  U64 intra = (wave == 0) ? maskT[lane] : 0ull;   // chunk 0 diagonal word
  __syncthreads();
  for (int c = 0; c < NWORD; ++c) {
    const U64* colp = maskT + (size_t)c * MROWS;
    int base = (c + 1) * 64;
    // ---- hoisted apply loads (independent of decide) ----
    U64 m[12];                               // 12*512 = 6144 >= max rows
#pragma unroll
    for (int q = 0; q < 12; ++q) {
      int i = base + q * 512 + t;
      int ic = (i > MROWS - 1) ? (MROWS - 1) : i;
      m[q] = colp[ic];
    }
    if (wave == 0) {
      // ---- decide (wave-0 local; ballots are per-wave) ----
      U64 vw = vws[c];
      bool alive = (((vw >> lane) & 1ull) != 0ull) && (sup[c * 64 + lane] == 0u);
      U64 aliveW = __ballot(alive);
      bool myconf = alive && ((intra & aliveW & low) != 0ull);
      U64 confW = __ballot(myconf);
      U64 keep = aliveW & ~confW;            // non-conflicted alive are kept
      U64 rem = confW;                       // resolve conflicted ascending
      while (rem) {
        int b = __ffsll((unsigned long long)rem) - 1;
        rem &= rem - 1;
        U64 Z = __ballot((intra & keep & low) == 0ull);
        if ((Z >> b) & 1ull) keep |= (1ull << b);
      }
      if (lane == 0) { keepw[c] = keep; kwsh = keep; }
      if (c + 1 < NWORD)                     // prefetch next diagonal word
        intra = maskT[(size_t)(c + 1) * MROWS + (c + 1) * 64 + lane];
    }
    __syncthreads();                         // kwsh + sup reads ordered
    U64 keep = kwsh;                         // 0 -> stores self-disable
#pragma unroll
    for (int q = 0; q < 12; ++q) {
      int i = base + q * 512 + t;
      if (i < PRE_N && (m[q] & keep)) sup[i] = 1u;
    }
    __syncthreads();                         // sup[] complete before decide c+1
  }
}

// ============================================================================
// K11: proposals: prefix-popcount ranks, first 300 kept boxes, zeros elsewhere
// ============================================================================
__global__ __launch_bounds__(256) void k_out(
    const U64* __restrict__ keepw, const float* __restrict__ sboxes,
    float* __restrict__ prop)
{
  __shared__ U64 kw[NWORD];
  __shared__ U32 pre[NWORD + 1];
  int t = threadIdx.x;
  if (t < NWORD) kw[t] = keepw[t];
  __syncthreads();
  if (t == 0) {
    U32 s = 0;
    for (int w = 0; w < NWORD; ++w) { pre[w] = s; s += (U32)__popcll(kw[w]); }
    pre[NWORD] = s;
  }
  for (int x = t; x < POST_N * 4; x += 256) prop[x] = 0.f;
  __syncthreads();
  for (int i = t; i < PRE_N; i += 256) {
    int w = i >> 6, b = i & 63;
    if ((kw[w] >> b) & 1ull) {
      U64 lowb = (b == 0) ? 0ull : (~0ull >> (64 - b));
      U32 r = pre[w] + (U32)__popcll(kw[w] & lowb);
      if (r < POST_N)
        *(float4*)&prop[(size_t)r*4] = *(const float4*)&sboxes[(size_t)i*4];
    }
  }
}

// ============================================================================
extern "C" void kernel_launch(void* const* d_in, const int* in_sizes, int n_in,
                              void* d_out, int out_size, void* d_ws, size_t ws_size,
                              hipStream_t stream)
{
  (void)in_sizes; (void)n_in; (void)out_size;
  if (ws_size < WS_NEED) return;   // scratch too small; bail safely

  const float* feats = (const float*)d_in[0];
  const float* ancs  = (const float*)d_in[1];
  const float* W_b   = (const float*)d_in[3];
  const float* b_b   = (const float*)d_in[4];
  const float* W_cls = (const float*)d_in[5];
  const float* b_cls = (const float*)d_in[6];
  const float* W_reg = (const float*)d_in[7];
  const float* b_reg = (const float*)d_in[8];

  float* out    = (float*)d_out;
  float* outCls = out;                 // 90000
  float* outReg = out + 90000;         // 360000
  float* prop   = out + 450000;        // 1200

  char* ws = (char*)d_ws;
  float* H      = (float*)(ws + OFF_H);
  float* boxes  = (float*)(ws + OFF_BOXES);
  U32*   keys   = (U32*)  (ws + OFF_KEYS);
  U64*   maskT  = (U64*)  (ws + OFF_MASKT);
  U64*   sel    = (U64*)  (ws + OFF_SEL);
  float* sboxes = (float*)(ws + OFF_SBOX);
  U64*   validw = (U64*)  (ws + OFF_VALIDW);
  U64*   keepw  = (U64*)  (ws + OFF_KEEPW);
  U32*   hist   = (U32*)  (ws + OFF_HIST);
  U32*   cnt    = (U32*)  (ws + OFF_CNT);
  U32*   tiebuf = (U32*)  (ws + OFF_TIE);

  k_gemm1<<<dim3(640), dim3(256), 0, stream>>>(feats, W_b, b_b, H,
                                               hist, cnt, (U32*)validw);
  k_heads<<<dim3(2500), dim3(256), 0, stream>>>(H, W_cls, b_cls, W_reg, b_reg,
                                                outCls, outReg);
  k_decode<<<dim3(352), dim3(256), 0, stream>>>(outCls, outReg, ancs,
                                                boxes, keys, hist);
  k_scan<<<dim3(1), dim3(256), 0, stream>>>(hist, cnt, 0);
  for (int lv = 1; lv <= 3; ++lv) {
    k_hist<<<dim3(352), dim3(256), 0, stream>>>(keys, hist, cnt, lv);
    k_scan<<<dim3(1), dim3(256), 0, stream>>>(hist, cnt, lv);
  }
  k_compact<<<dim3(352), dim3(256), 0, stream>>>(keys, cnt, sel, tiebuf);
  k_ties<<<dim3(1), dim3(256), 0, stream>>>(cnt, tiebuf, sel);
  k_rank<<<dim3(24), dim3(256), 0, stream>>>(sel, boxes, sboxes, validw);
  k_mask<<<dim3(94, 94), dim3(256), 0, stream>>>(sboxes, maskT);
  k_nms<<<dim3(1), dim3(512), 0, stream>>>(maskT, validw, keepw);
  k_out<<<dim3(1), dim3(256), 0, stream>>>(keepw, sboxes, prop);
}

// Round 17
// 526.758 us; speedup vs baseline: 3.8650x; 1.0067x over previous
//
#include <hip/hip_runtime.h>
#include <math.h>

typedef unsigned int U32;
typedef unsigned long long U64;

#define NBOX   90000
#define NPIX   10000
#define KDIM   1024
#define CBOT   512
#define PRE_N  6000
#define POST_N 300
#define NWORD  94      // ceil(6000/64)
#define MROWS  6016    // 94*64 rows allocated per column in maskT
#define NTIE   3072    // tie-buffer capacity (ties at T are O(1) for this data)

// ---------------- workspace layout (byte offsets, all 16B aligned) ----------
#define OFF_H       0ULL          // 10000*512*4   = 20480000
#define OFF_BOXES   20480000ULL   // 90000*4*4     = 1440000
#define OFF_KEYS    21920000ULL   // 90000*4       = 360000
#define OFF_MASKT   22280000ULL   // 94*6016*8     = 4524032 (column-major)
#define OFF_SEL     26804032ULL   // 6000*8        = 48000
#define OFF_SBOX    26852032ULL   // 6000*4*4      = 96000
#define OFF_VALIDW  26948032ULL   // 94*8 -> 768
#define OFF_KEEPW   26948800ULL   // 768 (unused since R17 fusion)
#define OFF_CNT     26950592ULL   // 64*4 = 256
#define OFF_HIST4   26950848ULL   // 4 levels * 256 * 4 = 4096
#define OFF_TIE     26954944ULL   // 3072*4 = 12288 -> ends at WS_NEED
#define WS_NEED     26967232ULL

// cnt[] slots: 8=n_gt atomic  9=n_tie atomic (0..2 retired: scans are local)

// ============================================================================
// Local radix-scan chain: every block recomputes the digit-selection scan for
// levels [0,levels) from the per-level global histograms. Parallel 256-wide
// reverse inclusive scan (Hillis-Steele, LDS) + atomicMax digit pick ==
// exact semantics of the old serial k_scan (break at largest d with
// suffix_from(d) >= target; d=0 fallback). Deterministic in every block.
// res[0]=prefix res[1]=target(need) res[2]=cgt res[3]=digit scratch.
// ============================================================================
__device__ __forceinline__ void scan_levels(
    const U32* __restrict__ histg, int levels, int t,
    U32* lh, U32* sfx, volatile U32* res)
{
  if (t == 0) { res[0] = 0; res[1] = PRE_N; res[2] = 0; }
  __syncthreads();
  for (int L = 0; L < levels; ++L) {
    if (t < 256) { U32 h = histg[L * 256 + t]; lh[t] = h; sfx[t] = h; }
    if (t == 0) res[3] = 0;
    __syncthreads();
    for (int off = 1; off < 256; off <<= 1) {
      U32 v = 0;
      if (t < 256) v = sfx[t] + ((t + off < 256) ? sfx[t + off] : 0);
      __syncthreads();
      if (t < 256) sfx[t] = v;
      __syncthreads();
    }
    if (t > 0 && t < 256 && sfx[t] >= res[1]) atomicMax((U32*)&res[3], (U32)t);
    __syncthreads();
    if (t == 0) {
      U32 d = res[3];
      U32 cum = (d < 255) ? sfx[d + 1] : 0;
      res[0] |= d << (24 - 8 * L);
      res[1] = res[1] - cum;
      res[2] += cum;
    }
    __syncthreads();
  }
}

// ============================================================================
// K1: h = relu(feats @ W_b + b_b)  fp32, 128x64 tile, 8x4 acc/thread, BK=16.
// EXACT R14 hot path (178us, VGPR=48, acc in AGPRs, zero spill). R15 lesson:
// no extra live state across the FMA loop. XCD remap (T1): FETCH ~55MB.
// Also zero-inits hist4/cnt/validw (block 0 only).
// ============================================================================
__global__ __launch_bounds__(256, 4) void k_gemm1(
    const float* __restrict__ A, const float* __restrict__ W,
    const float* __restrict__ bias, float* __restrict__ H,
    U32* __restrict__ hist4, U32* __restrict__ cnt, U32* __restrict__ validw32)
{
  int t = threadIdx.x;
  if (blockIdx.x == 0) {
    hist4[t] = 0; hist4[t + 256] = 0; hist4[t + 512] = 0; hist4[t + 768] = 0;
    if (t < 64)  cnt[t] = 0u;
    if (t < 188) validw32[t] = 0;
  }
  int bid = blockIdx.x;
  int c = bid & 7;                 // XCD under round-robin dispatch
  int s = bid >> 3;                // 0..79
  int x = s / 10;                  // 0..7  column block
  int yy = c * 10 + (s % 10);      // 0..79 row block; XCD-local A slab
  if (yy >= 79) return;            // 8 dead blocks
  __shared__ float As[16][132];   // [k][m], pad: bank stride 4 per k-row
  __shared__ float Bs[16][68];    // [k][n], 64 cols + pad
  int m0 = yy * 128, n0 = x * 64;
  int tm = t >> 4, tn = t & 15;
  int ar = t >> 1, ac = (t & 1) << 3;   // A stage: row ar, cols ac..ac+7
  int bk = t >> 4, bc = (t & 15) << 2;  // B stage: row bk, cols bc..bc+3
  float acc[8][4];
#pragma unroll
  for (int i = 0; i < 8; ++i)
#pragma unroll
    for (int j = 0; j < 4; ++j) acc[i][j] = 0.f;

  // prologue: first tile's loads
  int arow = m0 + ar;
  float4 a0 = make_float4(0.f,0.f,0.f,0.f), a1 = a0;
  if (arow < NPIX) {
    a0 = *(const float4*)&A[(size_t)arow * KDIM + ac];
    a1 = *(const float4*)&A[(size_t)arow * KDIM + ac + 4];
  }
  float4 b0 = *(const float4*)&W[(size_t)bk * CBOT + n0 + bc];

  for (int k0 = 0; k0 < KDIM; k0 += 16) {
    __syncthreads();                 // prior FMA readers done
    As[ac+0][ar] = a0.x; As[ac+1][ar] = a0.y; As[ac+2][ar] = a0.z; As[ac+3][ar] = a0.w;
    As[ac+4][ar] = a1.x; As[ac+5][ar] = a1.y; As[ac+6][ar] = a1.z; As[ac+7][ar] = a1.w;
    *(float4*)&Bs[bk][bc] = b0;
    __syncthreads();
    if (k0 + 16 < KDIM) {            // issue next-tile loads BEFORE FMA loop
      int kn = k0 + 16;
      if (arow < NPIX) {
        a0 = *(const float4*)&A[(size_t)arow * KDIM + kn + ac];
        a1 = *(const float4*)&A[(size_t)arow * KDIM + kn + ac + 4];
      }
      b0 = *(const float4*)&W[(size_t)(kn + bk) * CBOT + n0 + bc];
    }
#pragma unroll
    for (int kk = 0; kk < 16; ++kk) {
      float4 av0 = *(float4*)&As[kk][tm*8];      // 16-lane broadcast, no conflict
      float4 av1 = *(float4*)&As[kk][tm*8+4];
      float4 bv0 = *(float4*)&Bs[kk][tn*4];      // 2-way aliasing: free
      float am[8] = {av0.x,av0.y,av0.z,av0.w,av1.x,av1.y,av1.z,av1.w};
      float bm[4] = {bv0.x,bv0.y,bv0.z,bv0.w};
#pragma unroll
      for (int i = 0; i < 8; ++i)
#pragma unroll
        for (int j = 0; j < 4; ++j)
          acc[i][j] = fmaf(am[i], bm[j], acc[i][j]);
    }
  }
  float4 bb = *(const float4*)&bias[n0 + tn*4];
  float bm[4] = {bb.x, bb.y, bb.z, bb.w};
#pragma unroll
  for (int i = 0; i < 8; ++i) {
    int r = m0 + tm*8 + i;
    if (r < NPIX) {
      float4 o;
      o.x = fmaxf(acc[i][0] + bm[0], 0.f);
      o.y = fmaxf(acc[i][1] + bm[1], 0.f);
      o.z = fmaxf(acc[i][2] + bm[2], 0.f);
      o.w = fmaxf(acc[i][3] + bm[3], 0.f);
      *(float4*)&H[(size_t)r * CBOT + n0 + tn*4] = o;
    }
  }
}

// ============================================================================
// K2: cls = sigmoid(h@W_cls+b_cls), reg = h@W_reg+b_reg  (4 pixels / block)
// ============================================================================
__global__ __launch_bounds__(256) void k_heads(
    const float* __restrict__ H, const float* __restrict__ Wc,
    const float* __restrict__ bc, const float* __restrict__ Wr,
    const float* __restrict__ br, float* __restrict__ outCls,
    float* __restrict__ outReg)
{
  __shared__ float hs[4][516];
  int t = threadIdx.x;
  int p0 = blockIdx.x * 4;
  for (int q = t; q < 512; q += 256) {
    int row = q >> 7, off = (q & 127) << 2;
    *(float4*)&hs[row][off] = *(const float4*)&H[(size_t)(p0 + row) * CBOT + off];
  }
  __syncthreads();
  if (t < 180) {
    int pl = t / 45, c = t % 45;
    const float* wp; int stride; float bval;
    if (c < 9) { wp = Wc + c;       stride = 9;  bval = bc[c]; }
    else       { wp = Wr + (c - 9); stride = 36; bval = br[c - 9]; }
    float s = 0.f;
    const float* hrow = hs[pl];
    for (int k = 0; k < CBOT; k += 4) {
      float4 hv = *(const float4*)&hrow[k];
      s = fmaf(hv.x, wp[(size_t)(k+0)*stride], s);
      s = fmaf(hv.y, wp[(size_t)(k+1)*stride], s);
      s = fmaf(hv.z, wp[(size_t)(k+2)*stride], s);
      s = fmaf(hv.w, wp[(size_t)(k+3)*stride], s);
    }
    s += bval;
    int p = p0 + pl;
    if (c < 9) outCls[(size_t)p*9 + c] = 1.f / (1.f + expf(-s));
    else       outReg[(size_t)p*36 + (c - 9)] = s;
  }
}

// ============================================================================
// K3: decode boxes, size filter, sortable keys, level-0 histogram
// ============================================================================
__global__ __launch_bounds__(256) void k_decode(
    const float* __restrict__ outCls, const float* __restrict__ outReg,
    const float* __restrict__ ancs, float* __restrict__ boxes,
    U32* __restrict__ keys, U32* __restrict__ hist4)
{
  __shared__ U32 lh[256];
  int t = threadIdx.x;
  int tid = blockIdx.x * 256 + t;
  lh[t] = 0;
  __syncthreads();
  if (tid < NBOX) {
    float sc = outCls[tid];
    float4 of = *(const float4*)&outReg[(size_t)tid*4];
    float4 an = *(const float4*)&ancs[(size_t)tid*4];
    float cx = an.x + of.x * an.z;
    float cy = an.y + of.y * an.w;
    float ww = an.z * expf(of.z);
    float hh = an.w * expf(of.w);
    float x1 = fminf(fmaxf(cx - ww * 0.5f, 0.f), 1.f);
    float y1 = fminf(fmaxf(cy - hh * 0.5f, 0.f), 1.f);
    float x2 = fminf(fmaxf(cx + ww * 0.5f, 0.f), 1.f);
    float y2 = fminf(fmaxf(cy + hh * 0.5f, 0.f), 1.f);
    bool ok = ((x2 - x1) * 100.f >= 1.f) && ((y2 - y1) * 100.f >= 1.f);
    float msc = ok ? sc : -1.f;
    U32 u = __float_as_uint(msc);
    U32 key = (u & 0x80000000u) ? ~u : (u | 0x80000000u);
    keys[tid] = key;
    *(float4*)&boxes[(size_t)tid*4] = make_float4(x1, y1, x2, y2);
    atomicAdd(&lh[key >> 24], 1u);
  }
  __syncthreads();
  if (lh[t]) atomicAdd(&hist4[t], lh[t]);
}

// ============================================================================
// K5: filtered histogram for levels 1..3; prefix recomputed locally (no
// k_scan kernels, no cnt dependency).
// ============================================================================
__global__ __launch_bounds__(256) void k_hist(
    const U32* __restrict__ keys, U32* __restrict__ hist4, int level)
{
  __shared__ U32 lh[256];
  __shared__ U32 sfx[256];
  __shared__ U32 res[4];
  int t = threadIdx.x;
  scan_levels(hist4, level, t, lh, sfx, res);
  U32 prefix = res[0];
  lh[t] = 0;
  __syncthreads();
  int tid = blockIdx.x * 256 + t;
  if (tid < NBOX) {
    U32 k = keys[tid];
    int shift = 32 - 8*level;
    if ((k >> shift) == (prefix >> shift)) {
      U32 bin = (k >> (24 - 8*level)) & 0xFFu;
      atomicAdd(&lh[bin], 1u);
    }
  }
  __syncthreads();
  if (lh[t]) atomicAdd(&hist4[level * 256 + t], lh[t]);
}

// ============================================================================
// K6: compact: keys > T -> sel (unordered; rank pass sorts later);
//     keys == T -> tie buffer. T recomputed locally.
// ============================================================================
__global__ __launch_bounds__(256) void k_compact(
    const U32* __restrict__ keys, const U32* __restrict__ hist4,
    U32* __restrict__ cnt, U64* __restrict__ sel, U32* __restrict__ tiebuf)
{
  __shared__ U32 lh[256];
  __shared__ U32 sfx[256];
  __shared__ U32 res[4];
  int t = threadIdx.x;
  scan_levels(hist4, 4, t, lh, sfx, res);
  U32 T = res[0];
  int tid = blockIdx.x * 256 + t;
  if (tid >= NBOX) return;
  U32 k = keys[tid];
  if (k > T) {
    U32 p = atomicAdd(&cnt[8], 1u);
    sel[p] = ((U64)k << 32) | (U64)(0xFFFFFFFFu - (U32)tid);
  } else if (k == T) {
    U32 p = atomicAdd(&cnt[9], 1u);
    if (p < NTIE) tiebuf[p] = (U32)tid;
  }
}

// ============================================================================
// K7: resolve ==T ties by smallest index (stable top_k semantics);
//     need/cgt/T recomputed locally.
// ============================================================================
__global__ __launch_bounds__(256) void k_ties(
    const U32* __restrict__ hist4, U32* __restrict__ cnt,
    const U32* __restrict__ tiebuf, U64* __restrict__ sel)
{
  __shared__ U32 lh[256];
  __shared__ U32 sfx[256];
  __shared__ U32 res[4];
  __shared__ U32 tb[NTIE];
  int t = threadIdx.x;
  scan_levels(hist4, 4, t, lh, sfx, res);
  U32 T    = res[0];
  U32 need = res[1];
  U32 cgt  = res[2];
  U32 m = cnt[9]; if (m > (U32)NTIE) m = (U32)NTIE;
  for (U32 j = t; j < m; j += 256) tb[j] = tiebuf[j];
  __syncthreads();
  for (U32 x = t; x < m; x += 256) {
    U32 my = tb[x];
    U32 r = 0;
    for (U32 j = 0; j < m; ++j) r += (tb[j] < my) ? 1u : 0u;
    if (r < need) sel[cgt + r] = ((U64)T << 32) | (U64)(0xFFFFFFFFu - my);
  }
}

// ============================================================================
// K8: exact rank of each selected element (score desc, idx asc) -> sorted
// boxes + packed valid bits. 4-wide LDS compares (1500 iters vs 6000).
// Order-invariant wrt sel's (atomic-nondeterministic) storage order.
// ============================================================================
__global__ __launch_bounds__(256) void k_rank(
    const U64* __restrict__ sel, const float* __restrict__ boxes,
    float* __restrict__ sboxes, U64* __restrict__ validw)
{
  __shared__ __align__(16) U64 ss[PRE_N];
  int t = threadIdx.x;
  for (int j = t; j < PRE_N; j += 256) ss[j] = sel[j];
  __syncthreads();
  int i = blockIdx.x * 256 + t;
  if (i >= PRE_N) return;
  U64 C = ss[i];
  int r = 0;
  for (int j = 0; j < PRE_N; j += 4) {
    ulonglong2 v0 = *(const ulonglong2*)&ss[j];
    ulonglong2 v1 = *(const ulonglong2*)&ss[j + 2];
    r += (int)(v0.x > C) + (int)(v0.y > C) + (int)(v1.x > C) + (int)(v1.y > C);
  }
  U32 key = (U32)(C >> 32);
  U32 idx = 0xFFFFFFFFu - (U32)(C & 0xFFFFFFFFull);
  *(float4*)&sboxes[(size_t)r*4] = *(const float4*)&boxes[(size_t)idx*4];
  if (key & 0x80000000u)
    atomicOr(&validw[r >> 6], 1ull << (r & 63));
}

// ============================================================================
// K9: IoU > 0.7 bitmask, COLUMN-word-major: maskT[cw*MROWS + i] bit x =
//     iou(row i, box cw*64+x) > thr. Upper triangle + diagonal only (NMS
//     reads only i >= cw*64). Rows 6000..6015 in touched blocks written as 0.
// ============================================================================
__global__ __launch_bounds__(256) void k_mask(
    const float* __restrict__ sboxes, U64* __restrict__ maskT)
{
  int cw = blockIdx.x, rg = blockIdx.y;
  if (rg < cw) return;                       // lower triangle unused by NMS
  int t = threadIdx.x;
  int lane = t & 63, wv = t >> 6;
  int col = cw * 64 + lane;
  int cc = (col < PRE_N) ? col : (PRE_N - 1);
  float4 cb = *(const float4*)&sboxes[(size_t)cc*4];
  float areaC = (cb.z - cb.x) * (cb.w - cb.y);
  bool colok = (col < PRE_N);
  for (int rr = wv; rr < 64; rr += 4) {
    int row = rg * 64 + rr;
    U64 word = 0;
    if (row < PRE_N) {
      float4 rb = *(const float4*)&sboxes[(size_t)row*4];
      float areaR = (rb.z - rb.x) * (rb.w - rb.y);
      float ix1 = fmaxf(rb.x, cb.x), iy1 = fmaxf(rb.y, cb.y);
      float ix2 = fminf(rb.z, cb.z), iy2 = fminf(rb.w, cb.w);
      float inter = fmaxf(ix2 - ix1, 0.f) * fmaxf(iy2 - iy1, 0.f);
      float uni = areaR + areaC - inter;
      float iou = inter / fmaxf(uni, 1e-9f);
      word = __ballot(colok && (iou > 0.7f));
    }
    if (lane == 0) maskT[(size_t)cw * MROWS + row] = word;
  }
}

// ============================================================================
// K10: sequential-equivalent NMS — 8 WAVES, barrier phases, hoisted apply
// loads, PLUS fused proposal output (old k_out): keep words kept in LDS,
// epilogue does prefix-popcount + placement. Bitwise-deterministic.
// ============================================================================
__global__ __launch_bounds__(512, 1) void k_nms(
    const U64* __restrict__ maskT, const U64* __restrict__ validw,
    const float* __restrict__ sboxes, float* __restrict__ prop)
{
  __shared__ U32 sup[MROWS];
  __shared__ U64 vws[NWORD];
  __shared__ U64 kwS[NWORD];
  __shared__ U32 pre[NWORD + 1];
  __shared__ U64 kwsh;
  int t = threadIdx.x;                       // 0..511
  int wave = t >> 6, lane = t & 63;
  for (int i = t; i < MROWS; i += 512) sup[i] = 0;
  if (t < NWORD) vws[t] = validw[t];
  U64 low = (lane == 0) ? 0ull : (~0ull >> (64 - lane));
  U64 intra = (wave == 0) ? maskT[lane] : 0ull;   // chunk 0 diagonal word
  __syncthreads();
  for (int c = 0; c < NWORD; ++c) {
    const U64* colp = maskT + (size_t)c * MROWS;
    int base = (c + 1) * 64;
    // ---- hoisted apply loads (independent of decide) ----
    U64 m[12];                               // 12*512 = 6144 >= max rows
#pragma unroll
    for (int q = 0; q < 12; ++q) {
      int i = base + q * 512 + t;
      int ic = (i > MROWS - 1) ? (MROWS - 1) : i;
      m[q] = colp[ic];
    }
    if (wave == 0) {
      // ---- decide (wave-0 local; ballots are per-wave) ----
      U64 vw = vws[c];
      bool alive = (((vw >> lane) & 1ull) != 0ull) && (sup[c * 64 + lane] == 0u);
      U64 aliveW = __ballot(alive);
      bool myconf = alive && ((intra & aliveW & low) != 0ull);
      U64 confW = __ballot(myconf);
      U64 keep = aliveW & ~confW;            // non-conflicted alive are kept
      U64 rem = confW;                       // resolve conflicted ascending
      while (rem) {
        int b = __ffsll((unsigned long long)rem) - 1;
        rem &= rem - 1;
        U64 Z = __ballot((intra & keep & low) == 0ull);
        if ((Z >> b) & 1ull) keep |= (1ull << b);
      }
      if (lane == 0) { kwS[c] = keep; kwsh = keep; }
      if (c + 1 < NWORD)                     // prefetch next diagonal word
        intra = maskT[(size_t)(c + 1) * MROWS + (c + 1) * 64 + lane];
    }
    __syncthreads();                         // kwsh + sup reads ordered
    U64 keep = kwsh;                         // 0 -> stores self-disable
#pragma unroll
    for (int q = 0; q < 12; ++q) {
      int i = base + q * 512 + t;
      if (i < PRE_N && (m[q] & keep)) sup[i] = 1u;
    }
    __syncthreads();                         // sup[] complete before decide c+1
  }
  // ---- fused proposal output (old k_out) ----
  if (t == 0) {
    U32 s = 0;
    for (int w = 0; w < NWORD; ++w) { pre[w] = s; s += (U32)__popcll(kwS[w]); }
    pre[NWORD] = s;
  }
  for (int x = t; x < POST_N * 4; x += 512) prop[x] = 0.f;
  __syncthreads();
  for (int i = t; i < PRE_N; i += 512) {
    int w = i >> 6, b = i & 63;
    if ((kwS[w] >> b) & 1ull) {
      U64 lowb = (b == 0) ? 0ull : (~0ull >> (64 - b));
      U32 r = pre[w] + (U32)__popcll(kwS[w] & lowb);
      if (r < POST_N)
        *(float4*)&prop[(size_t)r*4] = *(const float4*)&sboxes[(size_t)i*4];
    }
  }
}

// ============================================================================
extern "C" void kernel_launch(void* const* d_in, const int* in_sizes, int n_in,
                              void* d_out, int out_size, void* d_ws, size_t ws_size,
                              hipStream_t stream)
{
  (void)in_sizes; (void)n_in; (void)out_size;
  if (ws_size < WS_NEED) return;   // scratch too small; bail safely

  const float* feats = (const float*)d_in[0];
  const float* ancs  = (const float*)d_in[1];
  const float* W_b   = (const float*)d_in[3];
  const float* b_b   = (const float*)d_in[4];
  const float* W_cls = (const float*)d_in[5];
  const float* b_cls = (const float*)d_in[6];
  const float* W_reg = (const float*)d_in[7];
  const float* b_reg = (const float*)d_in[8];

  float* out    = (float*)d_out;
  float* outCls = out;                 // 90000
  float* outReg = out + 90000;         // 360000
  float* prop   = out + 450000;        // 1200

  char* ws = (char*)d_ws;
  float* H      = (float*)(ws + OFF_H);
  float* boxes  = (float*)(ws + OFF_BOXES);
  U32*   keys   = (U32*)  (ws + OFF_KEYS);
  U64*   maskT  = (U64*)  (ws + OFF_MASKT);
  U64*   sel    = (U64*)  (ws + OFF_SEL);
  float* sboxes = (float*)(ws + OFF_SBOX);
  U64*   validw = (U64*)  (ws + OFF_VALIDW);
  U32*   cnt    = (U32*)  (ws + OFF_CNT);
  U32*   hist4  = (U32*)  (ws + OFF_HIST4);
  U32*   tiebuf = (U32*)  (ws + OFF_TIE);

  k_gemm1<<<dim3(640), dim3(256), 0, stream>>>(feats, W_b, b_b, H,
                                               hist4, cnt, (U32*)validw);
  k_heads<<<dim3(2500), dim3(256), 0, stream>>>(H, W_cls, b_cls, W_reg, b_reg,
                                                outCls, outReg);
  k_decode<<<dim3(352), dim3(256), 0, stream>>>(outCls, outReg, ancs,
                                                boxes, keys, hist4);
  for (int lv = 1; lv <= 3; ++lv)
    k_hist<<<dim3(352), dim3(256), 0, stream>>>(keys, hist4, lv);
  k_compact<<<dim3(352), dim3(256), 0, stream>>>(keys, hist4, cnt, sel, tiebuf);
  k_ties<<<dim3(1), dim3(256), 0, stream>>>(hist4, cnt, tiebuf, sel);
  k_rank<<<dim3(24), dim3(256), 0, stream>>>(sel, boxes, sboxes, validw);
  k_mask<<<dim3(94, 94), dim3(256), 0, stream>>>(sboxes, maskT);
  k_nms<<<dim3(1), dim3(512), 0, stream>>>(maskT, validw, sboxes, prop);
}

// Round 18
// 514.438 us; speedup vs baseline: 3.9575x; 1.0239x over previous
//
#include <hip/hip_runtime.h>
#include <math.h>

typedef unsigned int U32;
typedef unsigned long long U64;

#define NBOX   90000
#define NPIX   10000
#define KDIM   1024
#define CBOT   512
#define PRE_N  6000
#define POST_N 300
#define NWORD  94      // ceil(6000/64)
#define MROWS  6016    // 94*64 rows allocated per column in maskT
#define NTIE   3072    // tie-buffer capacity (ties at T are O(1) for this data)

// ---------------- workspace layout (byte offsets, all 16B aligned) ----------
#define OFF_H       0ULL          // 10000*512*4   = 20480000
#define OFF_BOXES   20480000ULL   // 90000*4*4     = 1440000
#define OFF_KEYS    21920000ULL   // 90000*4       = 360000
#define OFF_MASKT   22280000ULL   // 94*6016*8     = 4524032 (column-major)
#define OFF_SEL     26804032ULL   // 6000*8        = 48000
#define OFF_SBOX    26852032ULL   // 6000*4*4      = 96000
#define OFF_VALIDW  26948032ULL   // 94*8 -> 768
#define OFF_KEEPW   26948800ULL   // 768 (unused since R17 fusion)
#define OFF_CNT     26950592ULL   // 64*4 = 256
#define OFF_HIST4   26950848ULL   // 4 levels * 256 * 4 = 4096
#define OFF_TIE     26954944ULL   // 3072*4 = 12288 -> ends at WS_NEED
#define WS_NEED     26967232ULL

// cnt[] slots: 8=n_gt atomic  9=n_tie atomic

// ============================================================================
// Local radix-scan chain (R17): every consumer block recomputes digit
// selection from the per-level global histograms. Parallel 256-wide reverse
// inclusive scan + atomicMax digit pick == old serial k_scan semantics.
// res[0]=prefix res[1]=target(need) res[2]=cgt res[3]=digit scratch.
// ============================================================================
__device__ __forceinline__ void scan_levels(
    const U32* __restrict__ histg, int levels, int t,
    U32* lh, U32* sfx, volatile U32* res)
{
  if (t == 0) { res[0] = 0; res[1] = PRE_N; res[2] = 0; }
  __syncthreads();
  for (int L = 0; L < levels; ++L) {
    if (t < 256) { U32 h = histg[L * 256 + t]; lh[t] = h; sfx[t] = h; }
    if (t == 0) res[3] = 0;
    __syncthreads();
    for (int off = 1; off < 256; off <<= 1) {
      U32 v = 0;
      if (t < 256) v = sfx[t] + ((t + off < 256) ? sfx[t + off] : 0);
      __syncthreads();
      if (t < 256) sfx[t] = v;
      __syncthreads();
    }
    if (t > 0 && t < 256 && sfx[t] >= res[1]) atomicMax((U32*)&res[3], (U32)t);
    __syncthreads();
    if (t == 0) {
      U32 d = res[3];
      U32 cum = (d < 255) ? sfx[d + 1] : 0;
      res[0] |= d << (24 - 8 * L);
      res[1] = res[1] - cum;
      res[2] += cum;
    }
    __syncthreads();
  }
}

// ============================================================================
// K1: h = relu(feats @ W_b + b_b)  fp32, 64x64 tile, 4x4 acc/thread, BK=16.
// R17 diagnosis: 128x64 grid=632 -> 2.47 blocks/CU (Occupancy 19%), waits
// exposed. Retile M/N to 64x64 -> 1256 live blocks (4.9/CU). Per-output
// ascending-k single-chain preserved => H BITWISE IDENTICAL (only K-split
// would change rounding). Staging/read patterns same class as R14 (B-read
// 2-way aliasing = free). XCD remap: each XCD owns 20 row-blocks (5.1MB
// A-slab, L2-resident). R15 lesson: no extra live state across FMA loop.
// Also zero-inits hist4/cnt/validw (block 0 only).
// ============================================================================
__global__ __launch_bounds__(256, 4) void k_gemm1(
    const float* __restrict__ A, const float* __restrict__ W,
    const float* __restrict__ bias, float* __restrict__ H,
    U32* __restrict__ hist4, U32* __restrict__ cnt, U32* __restrict__ validw32)
{
  int t = threadIdx.x;
  if (blockIdx.x == 0) {
    hist4[t] = 0; hist4[t + 256] = 0; hist4[t + 512] = 0; hist4[t + 768] = 0;
    if (t < 64)  cnt[t] = 0u;
    if (t < 188) validw32[t] = 0;
  }
  int bid = blockIdx.x;
  int c = bid & 7;                 // XCD under round-robin dispatch
  int s = bid >> 3;                // 0..159
  int x = s / 20;                  // 0..7   column block
  int yy = c * 20 + (s % 20);      // 0..159 row block; XCD-local A slab
  if (yy >= 157) return;           // 24 dead blocks
  __shared__ float As[16][68];    // [k][m], pad keeps 16B alignment
  __shared__ float Bs[16][68];    // [k][n]
  int m0 = yy * 64, n0 = x * 64;
  int tm = t >> 4, tn = t & 15;
  int ar = t >> 2, ac = (t & 3) << 2;   // A stage: row ar, cols ac..ac+3
  int bk = t >> 4, bc = (t & 15) << 2;  // B stage: row bk, cols bc..bc+3
  float acc[4][4];
#pragma unroll
  for (int i = 0; i < 4; ++i)
#pragma unroll
    for (int j = 0; j < 4; ++j) acc[i][j] = 0.f;

  // prologue: first tile's loads
  int arow = m0 + ar;
  float4 a0 = make_float4(0.f,0.f,0.f,0.f);
  if (arow < NPIX) a0 = *(const float4*)&A[(size_t)arow * KDIM + ac];
  float4 b0 = *(const float4*)&W[(size_t)bk * CBOT + n0 + bc];

  for (int k0 = 0; k0 < KDIM; k0 += 16) {
    __syncthreads();                 // prior FMA readers done
    As[ac+0][ar] = a0.x; As[ac+1][ar] = a0.y;
    As[ac+2][ar] = a0.z; As[ac+3][ar] = a0.w;
    *(float4*)&Bs[bk][bc] = b0;
    __syncthreads();
    if (k0 + 16 < KDIM) {            // issue next-tile loads BEFORE FMA loop
      int kn = k0 + 16;
      if (arow < NPIX) a0 = *(const float4*)&A[(size_t)arow * KDIM + kn + ac];
      b0 = *(const float4*)&W[(size_t)(kn + bk) * CBOT + n0 + bc];
    }
#pragma unroll
    for (int kk = 0; kk < 16; ++kk) {
      float4 av = *(float4*)&As[kk][tm*4];       // 16-lane broadcast groups
      float4 bv = *(float4*)&Bs[kk][tn*4];       // 2-way aliasing: free
      float am[4] = {av.x, av.y, av.z, av.w};
      float bm[4] = {bv.x, bv.y, bv.z, bv.w};
#pragma unroll
      for (int i = 0; i < 4; ++i)
#pragma unroll
        for (int j = 0; j < 4; ++j)
          acc[i][j] = fmaf(am[i], bm[j], acc[i][j]);
    }
  }
  float4 bb = *(const float4*)&bias[n0 + tn*4];
  float bm[4] = {bb.x, bb.y, bb.z, bb.w};
#pragma unroll
  for (int i = 0; i < 4; ++i) {
    int r = m0 + tm*4 + i;
    if (r < NPIX) {
      float4 o;
      o.x = fmaxf(acc[i][0] + bm[0], 0.f);
      o.y = fmaxf(acc[i][1] + bm[1], 0.f);
      o.z = fmaxf(acc[i][2] + bm[2], 0.f);
      o.w = fmaxf(acc[i][3] + bm[3], 0.f);
      *(float4*)&H[(size_t)r * CBOT + n0 + tn*4] = o;
    }
  }
}

// ============================================================================
// K2: cls = sigmoid(h@W_cls+b_cls), reg = h@W_reg+b_reg  (4 pixels / block)
// ============================================================================
__global__ __launch_bounds__(256) void k_heads(
    const float* __restrict__ H, const float* __restrict__ Wc,
    const float* __restrict__ bc, const float* __restrict__ Wr,
    const float* __restrict__ br, float* __restrict__ outCls,
    float* __restrict__ outReg)
{
  __shared__ float hs[4][516];
  int t = threadIdx.x;
  int p0 = blockIdx.x * 4;
  for (int q = t; q < 512; q += 256) {
    int row = q >> 7, off = (q & 127) << 2;
    *(float4*)&hs[row][off] = *(const float4*)&H[(size_t)(p0 + row) * CBOT + off];
  }
  __syncthreads();
  if (t < 180) {
    int pl = t / 45, c = t % 45;
    const float* wp; int stride; float bval;
    if (c < 9) { wp = Wc + c;       stride = 9;  bval = bc[c]; }
    else       { wp = Wr + (c - 9); stride = 36; bval = br[c - 9]; }
    float s = 0.f;
    const float* hrow = hs[pl];
    for (int k = 0; k < CBOT; k += 4) {
      float4 hv = *(const float4*)&hrow[k];
      s = fmaf(hv.x, wp[(size_t)(k+0)*stride], s);
      s = fmaf(hv.y, wp[(size_t)(k+1)*stride], s);
      s = fmaf(hv.z, wp[(size_t)(k+2)*stride], s);
      s = fmaf(hv.w, wp[(size_t)(k+3)*stride], s);
    }
    s += bval;
    int p = p0 + pl;
    if (c < 9) outCls[(size_t)p*9 + c] = 1.f / (1.f + expf(-s));
    else       outReg[(size_t)p*36 + (c - 9)] = s;
  }
}

// ============================================================================
// K3: decode boxes, size filter, sortable keys, level-0 histogram
// ============================================================================
__global__ __launch_bounds__(256) void k_decode(
    const float* __restrict__ outCls, const float* __restrict__ outReg,
    const float* __restrict__ ancs, float* __restrict__ boxes,
    U32* __restrict__ keys, U32* __restrict__ hist4)
{
  __shared__ U32 lh[256];
  int t = threadIdx.x;
  int tid = blockIdx.x * 256 + t;
  lh[t] = 0;
  __syncthreads();
  if (tid < NBOX) {
    float sc = outCls[tid];
    float4 of = *(const float4*)&outReg[(size_t)tid*4];
    float4 an = *(const float4*)&ancs[(size_t)tid*4];
    float cx = an.x + of.x * an.z;
    float cy = an.y + of.y * an.w;
    float ww = an.z * expf(of.z);
    float hh = an.w * expf(of.w);
    float x1 = fminf(fmaxf(cx - ww * 0.5f, 0.f), 1.f);
    float y1 = fminf(fmaxf(cy - hh * 0.5f, 0.f), 1.f);
    float x2 = fminf(fmaxf(cx + ww * 0.5f, 0.f), 1.f);
    float y2 = fminf(fmaxf(cy + hh * 0.5f, 0.f), 1.f);
    bool ok = ((x2 - x1) * 100.f >= 1.f) && ((y2 - y1) * 100.f >= 1.f);
    float msc = ok ? sc : -1.f;
    U32 u = __float_as_uint(msc);
    U32 key = (u & 0x80000000u) ? ~u : (u | 0x80000000u);
    keys[tid] = key;
    *(float4*)&boxes[(size_t)tid*4] = make_float4(x1, y1, x2, y2);
    atomicAdd(&lh[key >> 24], 1u);
  }
  __syncthreads();
  if (lh[t]) atomicAdd(&hist4[t], lh[t]);
}

// ============================================================================
// K5: filtered histogram for levels 1..3; prefix recomputed locally.
// ============================================================================
__global__ __launch_bounds__(256) void k_hist(
    const U32* __restrict__ keys, U32* __restrict__ hist4, int level)
{
  __shared__ U32 lh[256];
  __shared__ U32 sfx[256];
  __shared__ U32 res[4];
  int t = threadIdx.x;
  scan_levels(hist4, level, t, lh, sfx, res);
  U32 prefix = res[0];
  lh[t] = 0;
  __syncthreads();
  int tid = blockIdx.x * 256 + t;
  if (tid < NBOX) {
    U32 k = keys[tid];
    int shift = 32 - 8*level;
    if ((k >> shift) == (prefix >> shift)) {
      U32 bin = (k >> (24 - 8*level)) & 0xFFu;
      atomicAdd(&lh[bin], 1u);
    }
  }
  __syncthreads();
  if (lh[t]) atomicAdd(&hist4[level * 256 + t], lh[t]);
}

// ============================================================================
// K6: compact: keys > T -> sel; keys == T -> tie buffer. T local.
// ============================================================================
__global__ __launch_bounds__(256) void k_compact(
    const U32* __restrict__ keys, const U32* __restrict__ hist4,
    U32* __restrict__ cnt, U64* __restrict__ sel, U32* __restrict__ tiebuf)
{
  __shared__ U32 lh[256];
  __shared__ U32 sfx[256];
  __shared__ U32 res[4];
  int t = threadIdx.x;
  scan_levels(hist4, 4, t, lh, sfx, res);
  U32 T = res[0];
  int tid = blockIdx.x * 256 + t;
  if (tid >= NBOX) return;
  U32 k = keys[tid];
  if (k > T) {
    U32 p = atomicAdd(&cnt[8], 1u);
    sel[p] = ((U64)k << 32) | (U64)(0xFFFFFFFFu - (U32)tid);
  } else if (k == T) {
    U32 p = atomicAdd(&cnt[9], 1u);
    if (p < NTIE) tiebuf[p] = (U32)tid;
  }
}

// ============================================================================
// K7: resolve ==T ties by smallest index; need/cgt/T local.
// ============================================================================
__global__ __launch_bounds__(256) void k_ties(
    const U32* __restrict__ hist4, U32* __restrict__ cnt,
    const U32* __restrict__ tiebuf, U64* __restrict__ sel)
{
  __shared__ U32 lh[256];
  __shared__ U32 sfx[256];
  __shared__ U32 res[4];
  __shared__ U32 tb[NTIE];
  int t = threadIdx.x;
  scan_levels(hist4, 4, t, lh, sfx, res);
  U32 T    = res[0];
  U32 need = res[1];
  U32 cgt  = res[2];
  U32 m = cnt[9]; if (m > (U32)NTIE) m = (U32)NTIE;
  for (U32 j = t; j < m; j += 256) tb[j] = tiebuf[j];
  __syncthreads();
  for (U32 x = t; x < m; x += 256) {
    U32 my = tb[x];
    U32 r = 0;
    for (U32 j = 0; j < m; ++j) r += (tb[j] < my) ? 1u : 0u;
    if (r < need) sel[cgt + r] = ((U64)T << 32) | (U64)(0xFFFFFFFFu - my);
  }
}

// ============================================================================
// K8: exact rank of each selected element -> sorted boxes + valid bits.
// 4-wide LDS compares. Order-invariant wrt sel storage order.
// ============================================================================
__global__ __launch_bounds__(256) void k_rank(
    const U64* __restrict__ sel, const float* __restrict__ boxes,
    float* __restrict__ sboxes, U64* __restrict__ validw)
{
  __shared__ __align__(16) U64 ss[PRE_N];
  int t = threadIdx.x;
  for (int j = t; j < PRE_N; j += 256) ss[j] = sel[j];
  __syncthreads();
  int i = blockIdx.x * 256 + t;
  if (i >= PRE_N) return;
  U64 C = ss[i];
  int r = 0;
  for (int j = 0; j < PRE_N; j += 4) {
    ulonglong2 v0 = *(const ulonglong2*)&ss[j];
    ulonglong2 v1 = *(const ulonglong2*)&ss[j + 2];
    r += (int)(v0.x > C) + (int)(v0.y > C) + (int)(v1.x > C) + (int)(v1.y > C);
  }
  U32 key = (U32)(C >> 32);
  U32 idx = 0xFFFFFFFFu - (U32)(C & 0xFFFFFFFFull);
  *(float4*)&sboxes[(size_t)r*4] = *(const float4*)&boxes[(size_t)idx*4];
  if (key & 0x80000000u)
    atomicOr(&validw[r >> 6], 1ull << (r & 63));
}

// ============================================================================
// K9: IoU > 0.7 bitmask, COLUMN-word-major, upper triangle + diagonal only.
// Rows 6000..6015 in touched blocks written as 0.
// ============================================================================
__global__ __launch_bounds__(256) void k_mask(
    const float* __restrict__ sboxes, U64* __restrict__ maskT)
{
  int cw = blockIdx.x, rg = blockIdx.y;
  if (rg < cw) return;                       // lower triangle unused by NMS
  int t = threadIdx.x;
  int lane = t & 63, wv = t >> 6;
  int col = cw * 64 + lane;
  int cc = (col < PRE_N) ? col : (PRE_N - 1);
  float4 cb = *(const float4*)&sboxes[(size_t)cc*4];
  float areaC = (cb.z - cb.x) * (cb.w - cb.y);
  bool colok = (col < PRE_N);
  for (int rr = wv; rr < 64; rr += 4) {
    int row = rg * 64 + rr;
    U64 word = 0;
    if (row < PRE_N) {
      float4 rb = *(const float4*)&sboxes[(size_t)row*4];
      float areaR = (rb.z - rb.x) * (rb.w - rb.y);
      float ix1 = fmaxf(rb.x, cb.x), iy1 = fmaxf(rb.y, cb.y);
      float ix2 = fminf(rb.z, cb.z), iy2 = fminf(rb.w, cb.w);
      float inter = fmaxf(ix2 - ix1, 0.f) * fmaxf(iy2 - iy1, 0.f);
      float uni = areaR + areaC - inter;
      float iou = inter / fmaxf(uni, 1e-9f);
      word = __ballot(colok && (iou > 0.7f));
    }
    if (lane == 0) maskT[(size_t)cw * MROWS + row] = word;
  }
}

// ============================================================================
// K10: sequential-equivalent NMS — 8 WAVES, barrier phases, hoisted apply
// loads, fused proposal output. Bitwise-deterministic, reference scan order.
// ============================================================================
__global__ __launch_bounds__(512, 1) void k_nms(
    const U64* __restrict__ maskT, const U64* __restrict__ validw,
    const float* __restrict__ sboxes, float* __restrict__ prop)
{
  __shared__ U32 sup[MROWS];
  __shared__ U64 vws[NWORD];
  __shared__ U64 kwS[NWORD];
  __shared__ U32 pre[NWORD + 1];
  __shared__ U64 kwsh;
  int t = threadIdx.x;                       // 0..511
  int wave = t >> 6, lane = t & 63;
  for (int i = t; i < MROWS; i += 512) sup[i] = 0;
  if (t < NWORD) vws[t] = validw[t];
  U64 low = (lane == 0) ? 0ull : (~0ull >> (64 - lane));
  U64 intra = (wave == 0) ? maskT[lane] : 0ull;   // chunk 0 diagonal word
  __syncthreads();
  for (int c = 0; c < NWORD; ++c) {
    const U64* colp = maskT + (size_t)c * MROWS;
    int base = (c + 1) * 64;
    // ---- hoisted apply loads (independent of decide) ----
    U64 m[12];                               // 12*512 = 6144 >= max rows
#pragma unroll
    for (int q = 0; q < 12; ++q) {
      int i = base + q * 512 + t;
      int ic = (i > MROWS - 1) ? (MROWS - 1) : i;
      m[q] = colp[ic];
    }
    if (wave == 0) {
      // ---- decide (wave-0 local; ballots are per-wave) ----
      U64 vw = vws[c];
      bool alive = (((vw >> lane) & 1ull) != 0ull) && (sup[c * 64 + lane] == 0u);
      U64 aliveW = __ballot(alive);
      bool myconf = alive && ((intra & aliveW & low) != 0ull);
      U64 confW = __ballot(myconf);
      U64 keep = aliveW & ~confW;            // non-conflicted alive are kept
      U64 rem = confW;                       // resolve conflicted ascending
      while (rem) {
        int b = __ffsll((unsigned long long)rem) - 1;
        rem &= rem - 1;
        U64 Z = __ballot((intra & keep & low) == 0ull);
        if ((Z >> b) & 1ull) keep |= (1ull << b);
      }
      if (lane == 0) { kwS[c] = keep; kwsh = keep; }
      if (c + 1 < NWORD)                     // prefetch next diagonal word
        intra = maskT[(size_t)(c + 1) * MROWS + (c + 1) * 64 + lane];
    }
    __syncthreads();                         // kwsh + sup reads ordered
    U64 keep = kwsh;                         // 0 -> stores self-disable
#pragma unroll
    for (int q = 0; q < 12; ++q) {
      int i = base + q * 512 + t;
      if (i < PRE_N && (m[q] & keep)) sup[i] = 1u;
    }
    __syncthreads();                         // sup[] complete before decide c+1
  }
  // ---- fused proposal output ----
  if (t == 0) {
    U32 s = 0;
    for (int w = 0; w < NWORD; ++w) { pre[w] = s; s += (U32)__popcll(kwS[w]); }
    pre[NWORD] = s;
  }
  for (int x = t; x < POST_N * 4; x += 512) prop[x] = 0.f;
  __syncthreads();
  for (int i = t; i < PRE_N; i += 512) {
    int w = i >> 6, b = i & 63;
    if ((kwS[w] >> b) & 1ull) {
      U64 lowb = (b == 0) ? 0ull : (~0ull >> (64 - b));
      U32 r = pre[w] + (U32)__popcll(kwS[w] & lowb);
      if (r < POST_N)
        *(float4*)&prop[(size_t)r*4] = *(const float4*)&sboxes[(size_t)i*4];
    }
  }
}

// ============================================================================
extern "C" void kernel_launch(void* const* d_in, const int* in_sizes, int n_in,
                              void* d_out, int out_size, void* d_ws, size_t ws_size,
                              hipStream_t stream)
{
  (void)in_sizes; (void)n_in; (void)out_size;
  if (ws_size < WS_NEED) return;   // scratch too small; bail safely

  const float* feats = (const float*)d_in[0];
  const float* ancs  = (const float*)d_in[1];
  const float* W_b   = (const float*)d_in[3];
  const float* b_b   = (const float*)d_in[4];
  const float* W_cls = (const float*)d_in[5];
  const float* b_cls = (const float*)d_in[6];
  const float* W_reg = (const float*)d_in[7];
  const float* b_reg = (const float*)d_in[8];

  float* out    = (float*)d_out;
  float* outCls = out;                 // 90000
  float* outReg = out + 90000;         // 360000
  float* prop   = out + 450000;        // 1200

  char* ws = (char*)d_ws;
  float* H      = (float*)(ws + OFF_H);
  float* boxes  = (float*)(ws + OFF_BOXES);
  U32*   keys   = (U32*)  (ws + OFF_KEYS);
  U64*   maskT  = (U64*)  (ws + OFF_MASKT);
  U64*   sel    = (U64*)  (ws + OFF_SEL);
  float* sboxes = (float*)(ws + OFF_SBOX);
  U64*   validw = (U64*)  (ws + OFF_VALIDW);
  U32*   cnt    = (U32*)  (ws + OFF_CNT);
  U32*   hist4  = (U32*)  (ws + OFF_HIST4);
  U32*   tiebuf = (U32*)  (ws + OFF_TIE);

  k_gemm1<<<dim3(1280), dim3(256), 0, stream>>>(feats, W_b, b_b, H,
                                                hist4, cnt, (U32*)validw);
  k_heads<<<dim3(2500), dim3(256), 0, stream>>>(H, W_cls, b_cls, W_reg, b_reg,
                                                outCls, outReg);
  k_decode<<<dim3(352), dim3(256), 0, stream>>>(outCls, outReg, ancs,
                                                boxes, keys, hist4);
  for (int lv = 1; lv <= 3; ++lv)
    k_hist<<<dim3(352), dim3(256), 0, stream>>>(keys, hist4, lv);
  k_compact<<<dim3(352), dim3(256), 0, stream>>>(keys, hist4, cnt, sel, tiebuf);
  k_ties<<<dim3(1), dim3(256), 0, stream>>>(hist4, cnt, tiebuf, sel);
  k_rank<<<dim3(24), dim3(256), 0, stream>>>(sel, boxes, sboxes, validw);
  k_mask<<<dim3(94, 94), dim3(256), 0, stream>>>(sboxes, maskT);
  k_nms<<<dim3(1), dim3(512), 0, stream>>>(maskT, validw, sboxes, prop);
}